// Round 8
// baseline (110.397 us; speedup 1.0000x reference)
//
#include <hip/hip_runtime.h>

// PiecewiseSparseMLP: B=262144 rows, K=32 experts (10 -> 20 -> 1), distance-softmax gating.
// Round 8: R7 MFMA structure with (1) LDS cut 38.4->26 KB (A-frags stored only for the
// 20 valid hidden rows; lanes m>=20 use a zero frag) -> 6 blocks/CU via
// __launch_bounds__(256,6), grid=2048 (1 tile/wave) to fill 24 waves/CU;
// (2) epilogue dot via packed v_pk_max/v_pk_fma_f32 (float2) -> half the scalar ops;
// (3) per-pair shuffles removed: gates pre-exchanged once (gx = shfl_xor 32), partials
// combined locally; b2 folded into the gating loop via a C-layout b2 table.
// Register risk: live ~80 vs cap ~84 -> expert loop unroll 1 (watch WRITE_SIZE for spill).

#define KX 32
#define DIN 10
#define DH 20

typedef short bf16x8 __attribute__((ext_vector_type(8)));
typedef float f32x16 __attribute__((ext_vector_type(16)));
typedef float v2f    __attribute__((ext_vector_type(2)));

#define ZERO16 {0.f,0.f,0.f,0.f, 0.f,0.f,0.f,0.f, 0.f,0.f,0.f,0.f, 0.f,0.f,0.f,0.f}

__device__ inline unsigned short f2bf(float f) {   // fp32 -> bf16 RNE
    unsigned int u = __float_as_uint(f);
    unsigned int r = u + 0x7fffu + ((u >> 16) & 1u);
    return (unsigned short)(r >> 16);
}

union BFU { bf16x8 v; unsigned short s[8]; };

__global__ __launch_bounds__(256, 6) void moe_kernel(
    const float* __restrict__ x,      // [B,10]
    const float* __restrict__ W1,     // [32,20,10]
    const float* __restrict__ b1,     // [32,20]
    const float* __restrict__ W2,     // [32,1,20]
    const float* __restrict__ b2,     // [32]
    const float* __restrict__ proto,  // [32,10]
    float* __restrict__ out,          // [B]
    int B)
{
    __shared__ bf16x8 s_af[KX * 40];   // A-frags, valid hidden rows only (20 KB)
    __shared__ float  s_w2[KX * 32];   // W2 in C-layout order per half (4 KB)
    __shared__ bf16x8 s_pf[64];        // proto A-frag (1 KB)
    __shared__ float  s_pn2[32];       // ||proto||^2, C-layout order
    __shared__ float  s_b2c[32];       // b2, C-layout order

    const int tid = threadIdx.x;

    // ---- build LDS tables ----
    for (int idx = tid; idx < KX * 40; idx += 256) {
        const int e = idx / 40, rem = idx - e * 40;
        const int hf = rem / 20, m = rem - hf * 20;
        BFU u;
#pragma unroll
        for (int j = 0; j < 8; ++j) {
            const int kk = hf * 8 + j;
            float v = 0.f;
            if (kk < DIN) v = W1[(e * DH + m) * DIN + kk];
            else if (kk == DIN) v = b1[e * DH + m];   // bias slot (x_ext[10]=1)
            u.s[j] = f2bf(v);
        }
        s_af[idx] = u.v;
    }
    for (int idx = tid; idx < KX * 32; idx += 256) {
        const int e = idx >> 5, rem = idx & 31;
        const int hf = rem >> 4, q = rem & 15;
        const int hid = (q & 3) + 8 * (q >> 2) + 4 * hf;
        s_w2[idx] = (hid < DH) ? W2[e * DH + hid] : 0.f;
    }
    if (tid < 64) {
        const int m = tid & 31, kb = (tid >> 5) * 8;
        BFU u;
#pragma unroll
        for (int j = 0; j < 8; ++j) {
            const int kk = kb + j;
            u.s[j] = f2bf(kk < DIN ? proto[m * DIN + kk] : 0.f);
        }
        s_pf[tid] = u.v;
    }
    if (tid < 32) {
        const int hf = tid >> 4, q = tid & 15;
        const int p = (q & 3) + 8 * (q >> 2) + 4 * hf;
        float s = 0.f;
#pragma unroll
        for (int i = 0; i < DIN; ++i) { const float v = proto[p * DIN + i]; s = fmaf(v, v, s); }
        s_pn2[tid] = s;
        s_b2c[tid] = b2[p];
    }
    __syncthreads();

    const int lane = tid & 63;
    const int wave = tid >> 6;
    const int half = lane >> 5;
    const int col  = lane & 31;

    const int row = (blockIdx.x * 4 + wave) * 32 + col;
    const int rr = (row < B) ? row : (B - 1);

    // ---- B-frag: x_ext[rr][half*8 .. +7]; slot 10 = 1.0 (bias) ----
    float xe[8];
    const float* xr = x + (size_t)rr * DIN;
    if (half == 0) {
#pragma unroll
        for (int i = 0; i < 4; ++i) {
            const float2 v = *(const float2*)(xr + 2 * i);
            xe[2 * i] = v.x; xe[2 * i + 1] = v.y;
        }
    } else {
        const float2 v = *(const float2*)(xr + 8);
        xe[0] = v.x; xe[1] = v.y; xe[2] = 1.f;
        xe[3] = 0.f; xe[4] = 0.f; xe[5] = 0.f; xe[6] = 0.f; xe[7] = 0.f;
    }
    BFU xu;
#pragma unroll
    for (int j = 0; j < 8; ++j) xu.s[j] = f2bf(xe[j]);
    const bf16x8 xfrag = xu.v;

    // ||x||^2 (fp32): half0 sums its 8, half1 only x[8],x[9]
    float part;
    if (half == 0) {
        part = 0.f;
#pragma unroll
        for (int j = 0; j < 8; ++j) part = fmaf(xe[j], xe[j], part);
    } else {
        part = fmaf(xe[0], xe[0], xe[1] * xe[1]);
    }
    const float xn2 = part + __shfl_xor(part, 32);

    // ---- gating MFMA + gates; fold b2 terms in here ----
    f32x16 zg = ZERO16;
    const f32x16 dotg = __builtin_amdgcn_mfma_f32_32x32x16_bf16(s_pf[lane], xfrag, zg, 0, 0, 0);

    float gate[16], gx[16];
    float dsum = 0.f, nsum = 0.f;
    {
        const v2f* pn2v = (const v2f*)(s_pn2 + half * 16);
        const float* b2c = s_b2c + half * 16;
#pragma unroll
        for (int i = 0; i < 8; ++i) {
            v2f dv = v2f{dotg[2 * i], dotg[2 * i + 1]};
            v2f s2 = pn2v[i] + v2f{xn2, xn2};
            v2f d2 = __builtin_elementwise_fma(dv, v2f{-2.f, -2.f}, s2);
            d2 = __builtin_elementwise_max(d2, v2f{0.f, 0.f});
            const float g0 = __expf(-__fsqrt_rn(d2.x));
            const float g1 = __expf(-__fsqrt_rn(d2.y));
            gate[2 * i] = g0; gate[2 * i + 1] = g1;
            dsum += g0 + g1;
            nsum = fmaf(g0, b2c[2 * i], nsum);
            nsum = fmaf(g1, b2c[2 * i + 1], nsum);
        }
#pragma unroll
        for (int q = 0; q < 16; ++q) gx[q] = __shfl_xor(gate[q], 32);
    }

    // ---- expert loop: pairs (elo, elo+4); partials combined locally via gx ----
    const int mrow = col;
#pragma unroll 1
    for (int j = 0; j < 16; ++j) {
        const int elo = (j & 3) + 8 * (j >> 2);
        const int ehi = elo + 4;

        bf16x8 alo = {0, 0, 0, 0, 0, 0, 0, 0};
        bf16x8 ahi = {0, 0, 0, 0, 0, 0, 0, 0};
        if (mrow < DH) {
            alo = s_af[elo * 40 + half * 20 + mrow];
            ahi = s_af[ehi * 40 + half * 20 + mrow];
        }
        f32x16 z0 = ZERO16, z1 = ZERO16;
        const f32x16 clo = __builtin_amdgcn_mfma_f32_32x32x16_bf16(alo, xfrag, z0, 0, 0, 0);
        const f32x16 chi = __builtin_amdgcn_mfma_f32_32x32x16_bf16(ahi, xfrag, z1, 0, 0, 0);

        const v2f* w2lo = (const v2f*)(s_w2 + elo * 32 + half * 16);
        const v2f* w2hi = (const v2f*)(s_w2 + ehi * 32 + half * 16);
        v2f plov = v2f{0.f, 0.f}, phiv = v2f{0.f, 0.f};
#pragma unroll
        for (int i = 0; i < 8; ++i) {
            v2f cl = __builtin_elementwise_max(v2f{clo[2 * i], clo[2 * i + 1]}, v2f{0.f, 0.f});
            v2f ch = __builtin_elementwise_max(v2f{chi[2 * i], chi[2 * i + 1]}, v2f{0.f, 0.f});
            plov = __builtin_elementwise_fma(cl, w2lo[i], plov);
            phiv = __builtin_elementwise_fma(ch, w2hi[i], phiv);
        }
        const float pplo = plov.x + plov.y;
        const float pphi = phiv.x + phiv.y;

        // half0 lane: own expert = elo (partial pplo), other = ehi (pphi)
        // half1 lane: own expert = ehi (partial pphi), other = elo (pplo)
        const float p_own = half ? pphi : pplo;
        const float p_oth = half ? pplo : pphi;
        nsum = fmaf(gate[j], p_own, nsum);
        nsum = fmaf(gx[j],   p_oth, nsum);
    }

    // ---- cross-half combine & write ----
    nsum += __shfl_xor(nsum, 32);
    dsum += __shfl_xor(dsum, 32);
    if (half == 0 && row < B) out[row] = nsum / dsum;
}

extern "C" void kernel_launch(void* const* d_in, const int* in_sizes, int n_in,
                              void* d_out, int out_size, void* d_ws, size_t ws_size,
                              hipStream_t stream) {
    const float* x     = (const float*)d_in[0];
    const float* W1    = (const float*)d_in[1];
    const float* b1    = (const float*)d_in[2];
    const float* W2    = (const float*)d_in[3];
    const float* b2    = (const float*)d_in[4];
    const float* proto = (const float*)d_in[5];
    float* out = (float*)d_out;

    const int B = out_size;            // D_OUT = 1
    const int rows_per_block = 4 * 32; // 4 waves x 1 tile x 32 rows
    const int grid = (B + rows_per_block - 1) / rows_per_block;
    hipLaunchKernelGGL(moe_kernel, dim3(grid), dim3(256), 0, stream,
                       x, W1, b1, W2, b2, proto, out, B);
}